// Round 2
// baseline (1360.741 us; speedup 1.0000x reference)
//
#include <hip/hip_runtime.h>
#include <math.h>

#define HH 128
#define HP 64   // u32 pairs per 128-feature row

typedef __attribute__((ext_vector_type(8))) short short8;
typedef __attribute__((ext_vector_type(4))) float float4v;
typedef __attribute__((ext_vector_type(4))) unsigned uint4v;

// ---------- helpers ----------
__device__ __forceinline__ float blo(unsigned w){ return __uint_as_float(w << 16); }
__device__ __forceinline__ float bhi(unsigned w){ return __uint_as_float(w & 0xffff0000u); }
__device__ __forceinline__ unsigned short f2b(float x){
  unsigned u = __float_as_uint(x);
  u += 0x7fffu + ((u >> 16) & 1u);           // RNE to bf16
  return (unsigned short)(u >> 16);
}
__device__ __forceinline__ unsigned pack2(float a, float b){
  return (unsigned)f2b(a) | ((unsigned)f2b(b) << 16);
}
__device__ __forceinline__ float silu_f(float x){ return x / (1.f + __expf(-x)); }

// ---------- 1) per-node precompute: A = h@W[0:128] + bias, B = h@W[128:256] ----------
__global__ __launch_bounds__(256) void precompute_kernel(
    const float* __restrict__ h, const float* __restrict__ W,
    const float* __restrict__ bias,
    unsigned* __restrict__ Aout, unsigned* __restrict__ Bout, int N)
{
  __shared__ unsigned Wl[256 * HP];           // 64 KB, rows 0..255 packed bf16
  int t = threadIdx.x;
  const float2* W2 = (const float2*)W;
  for (int i = t; i < 256 * HP; i += 256) {
    float2 w = W2[i];
    Wl[i] = pack2(w.x, w.y);
  }
  __syncthreads();

  int wid = blockIdx.x * 4 + (t >> 6);
  int nw  = gridDim.x * 4;
  int jp  = t & 63;
  for (int n = wid; n < N; n += nw) {
    const float4* hn = (const float4*)(h + (size_t)n * HH);
    float a0 = 0.f, a1 = 0.f, b0 = 0.f, b1 = 0.f;
    #pragma unroll 8
    for (int k4 = 0; k4 < 32; ++k4) {
      float4 hv = hn[k4];                     // wave-uniform broadcast load
      float xs[4] = {hv.x, hv.y, hv.z, hv.w};
      #pragma unroll
      for (int u = 0; u < 4; ++u) {
        int k = 4 * k4 + u;
        unsigned wa = Wl[k * HP + jp];
        unsigned wb = Wl[(128 + k) * HP + jp];
        a0 += xs[u] * blo(wa); a1 += xs[u] * bhi(wa);
        b0 += xs[u] * blo(wb); b1 += xs[u] * bhi(wb);
      }
    }
    a0 += bias[2 * jp]; a1 += bias[2 * jp + 1];
    Aout[(size_t)n * HP + jp] = pack2(a0, a1);
    Bout[(size_t)n * HP + jp] = pack2(b0, b1);
  }
}

// ---------- 2) MFMA edge kernels: MODE 0 = edge MLP (att -> h_agg), MODE 1 = coord MLP (-> x_agg) ----------
// v2: tail-dot via MFMA (T redistribute), W2 B-fragments in registers (no W2Ts LDS),
// double-buffered per-tile staging, gathers issued under the tail-MFMA phase.
template<int MODE>
__global__ __launch_bounds__(256, 4) void edge_kernel(
    const unsigned* __restrict__ Apart, const unsigned* __restrict__ Bpart,
    const float* __restrict__ W1,       // (276,128); rows 256..275 = tail
    const float* __restrict__ W2, const float* __restrict__ b2,
    const float* __restrict__ Wv,       // Wa (mode0) or Wc3 (mode1), [128]
    const float* __restrict__ ba_p,     // ba (mode0), unused mode1
    const int* __restrict__ src, const int* __restrict__ dst,
    const float* __restrict__ coords, const float* __restrict__ afeat,
    float* __restrict__ out_agg, int E)
{
  // mhl: stride 68 u32 -> b128 frag reads 2-way (free)
  __shared__ unsigned mhl[32 * 68];                 // 8.5 KB bf16-pairs
  __shared__ float    T[32 * 132];                  // 16.9 KB tail-MFMA out (stride 132: 2-way writes)
  __shared__ unsigned short tailsA[2][32 * 40];     // 5 KB: A-frag layout [edge][k], k>=20 zero
  __shared__ float    dif[2][32 * 4];               // dx,dy,dz,rad
  __shared__ int      sl[2][32], dl[2][32];
  __shared__ float    p_lds[4][16];

  const int t = threadIdx.x;
  const int lane = t & 63;
  const int w = t >> 6;
  const int mtile = w >> 1;                   // 0/1 (16-edge half)
  const int nhalf = w & 1;                    // 0/1 (64-col half)
  const int col = lane & 15;
  const int quad = lane >> 4;
  const int n0 = nhalf * 64 + col;            // + nt*16

  // zero tailsA fully once (k=20..39 pad must stay 0; stage only writes k<20)
  for (int i = t; i < 2 * 32 * 20; i += 256) ((unsigned*)tailsA)[i] = 0u;

  // ---- persistent register fragments ----
  uint4v w2f[4][4];                           // layer-2 B-frags [nt][ks]
  #pragma unroll
  for (int nt = 0; nt < 4; ++nt) {
    const int n = n0 + nt * 16;
    #pragma unroll
    for (int ks = 0; ks < 4; ++ks) {
      const int kb = ks * 32 + quad * 8;
      unsigned u0 = pack2(W2[(size_t)(kb+0)*128+n], W2[(size_t)(kb+1)*128+n]);
      unsigned u1 = pack2(W2[(size_t)(kb+2)*128+n], W2[(size_t)(kb+3)*128+n]);
      unsigned u2 = pack2(W2[(size_t)(kb+4)*128+n], W2[(size_t)(kb+5)*128+n]);
      unsigned u3 = pack2(W2[(size_t)(kb+6)*128+n], W2[(size_t)(kb+7)*128+n]);
      w2f[nt][ks] = (uint4v){u0, u1, u2, u3};
    }
  }
  uint4v wtf[4];                              // tail B-frags (W1 rows 256..275, K=32 zero-pad)
  #pragma unroll
  for (int nt = 0; nt < 4; ++nt) {
    const int n = n0 + nt * 16;
    unsigned u[4];
    #pragma unroll
    for (int i = 0; i < 4; ++i) {
      const int k0 = quad * 8 + 2 * i;
      float a = (k0     < 20) ? W1[(size_t)(256 + k0    ) * 128 + n] : 0.f;
      float b = (k0 + 1 < 20) ? W1[(size_t)(256 + k0 + 1) * 128 + n] : 0.f;
      u[i] = pack2(a, b);
    }
    wtf[nt] = (uint4v){u[0], u[1], u[2], u[3]};
  }
  float b2reg[4], wvreg[4];
  #pragma unroll
  for (int nt = 0; nt < 4; ++nt) {
    b2reg[nt] = b2[n0 + nt * 16];
    wvreg[nt] = Wv[n0 + nt * 16];
  }
  const float bav = (MODE == 0) ? ba_p[0] : 0.f;

  __syncthreads();                            // pad zeros visible before first stage

  // ---- stage per-edge scalars + tail A-fragment for tile into buffer b ----
  auto stage = [&](int tl, int b) {
    const int e0s = tl * 32;
    if (t < 32) {
      int eg = e0s + t;
      int s = 0, d = 0;
      if (eg < E) { s = src[eg]; d = dst[eg]; }
      sl[b][t] = s; dl[b][t] = d;
      float dx = coords[s*3+0] - coords[d*3+0];
      float dy = coords[s*3+1] - coords[d*3+1];
      float dz = coords[s*3+2] - coords[d*3+2];
      float rad = sqrtf(dx*dx + dy*dy + dz*dz);
      dif[b][t*4+0] = dx; dif[b][t*4+1] = dy;
      dif[b][t*4+2] = dz; dif[b][t*4+3] = rad;
      unsigned* ta = (unsigned*)&tailsA[b][t * 40];
      ta[0] = pack2(rad, fabsf(dx));
      ta[1] = pack2(fabsf(dy), fabsf(dz));
    }
    #pragma unroll
    for (int i = t; i < 512; i += 256) {
      int e = i >> 4, f = i & 15;
      int eg = e0s + e;
      tailsA[b][e * 40 + 4 + f] =
          (eg < E) ? f2b(afeat[(size_t)eg * 16 + f]) : (unsigned short)0;
    }
  };

  const int ntiles = (E + 31) >> 5;
  int tile = blockIdx.x;
  if (tile < ntiles) stage(tile, 0);
  int buf = 0;

  for (; tile < ntiles; tile += gridDim.x, buf ^= 1) {
    __syncthreads();                          // stage[buf] visible; prev-tile LDS reads done
    const int e0 = tile * 32;
    const int eb = w * 8;

    // ---- issue long-latency gathers now; consume after next barrier ----
    unsigned wa[8], wb[8];
    #pragma unroll
    for (int i = 0; i < 8; ++i) {
      wa[i] = Apart[(size_t)sl[buf][eb + i] * HP + lane];
      wb[i] = Bpart[(size_t)dl[buf][eb + i] * HP + lane];
    }

    // ---- tail MFMA: T[edge][n] = tails(20d) @ W1tail ----
    {
      const unsigned short* ap = &tailsA[buf][(mtile * 16 + col) * 40 + quad * 8];
      short8 af = __builtin_bit_cast(short8, *(const uint4v*)ap);
      float4v acct[4] = {{0,0,0,0},{0,0,0,0},{0,0,0,0},{0,0,0,0}};
      #pragma unroll
      for (int nt = 0; nt < 4; ++nt)
        acct[nt] = __builtin_amdgcn_mfma_f32_16x16x32_bf16(
            af, __builtin_bit_cast(short8, wtf[nt]), acct[nt], 0, 0, 0);
      #pragma unroll
      for (int nt = 0; nt < 4; ++nt)
        #pragma unroll
        for (int r = 0; r < 4; ++r)
          T[(mtile * 16 + quad * 4 + r) * 132 + n0 + nt * 16] = acct[nt][r];
    }
    __syncthreads();                          // T ready

    // ---- phase A: combine gathered A/B parts + tail, silu, pack to mhl ----
    #pragma unroll
    for (int i = 0; i < 8; ++i) {
      const int e = eb + i;
      float2 tv = *(const float2*)&T[e * 132 + 2 * lane];
      float t0 = blo(wa[i]) + blo(wb[i]) + tv.x;
      float t1 = bhi(wa[i]) + bhi(wb[i]) + tv.y;
      mhl[e * 68 + lane] = pack2(silu_f(t0), silu_f(t1));
    }
    __syncthreads();                          // mhl ready

    // ---- phase B: layer 2 via MFMA (B-frags in registers) ----
    float4v acc[4] = {{0,0,0,0},{0,0,0,0},{0,0,0,0},{0,0,0,0}};
    {
      const unsigned* abase = &mhl[(mtile * 16 + col) * 68 + quad * 4];
      #pragma unroll
      for (int ks = 0; ks < 4; ++ks) {
        short8 af = __builtin_bit_cast(short8, *(const uint4v*)(abase + ks * 16));
        #pragma unroll
        for (int nt = 0; nt < 4; ++nt)
          acc[nt] = __builtin_amdgcn_mfma_f32_16x16x32_bf16(
              af, __builtin_bit_cast(short8, w2f[nt][ks]), acc[nt], 0, 0, 0);
      }
    }

    // ---- epilogue: bias + silu (in place) + head dot, cross-wave reduce ----
    float p[4] = {0.f, 0.f, 0.f, 0.f};
    #pragma unroll
    for (int nt = 0; nt < 4; ++nt)
      #pragma unroll
      for (int r = 0; r < 4; ++r) {
        float v = silu_f(acc[nt][r] + b2reg[nt]);
        acc[nt][r] = v;                       // reuse acc as vv (register economy)
        p[r] += v * wvreg[nt];
      }
    #pragma unroll
    for (int r = 0; r < 4; ++r) {
      #pragma unroll
      for (int off = 1; off < 16; off <<= 1) p[r] += __shfl_xor(p[r], off, 64);
    }
    if (col == 0) {
      #pragma unroll
      for (int r = 0; r < 4; ++r) p_lds[w][quad * 4 + r] = p[r];
    }
    __syncthreads();                          // p_lds ready

    // ---- scatter ----
    #pragma unroll
    for (int r = 0; r < 4; ++r) {
      const int le = quad * 4 + r;
      const int ei = mtile * 16 + le;
      const int eg = e0 + ei;
      const float pfull = p_lds[w][le] + p_lds[w ^ 1][le];
      if (MODE == 0) {
        if (eg < E) {
          float att = 1.f / (1.f + __expf(-(pfull + bav)));
          int d = dl[buf][ei];
          #pragma unroll
          for (int nt = 0; nt < 4; ++nt)
            unsafeAtomicAdd(&out_agg[(size_t)d * HH + n0 + nt * 16], att * acc[nt][r]);
        }
      } else {
        if (nhalf == 0 && eg < E && col < 3) {
          float rad = dif[buf][ei * 4 + 3];
          float fac = pfull / (rad + 1.f);
          unsafeAtomicAdd(&out_agg[(size_t)dl[buf][ei] * 3 + col],
                          fac * dif[buf][ei * 4 + col]);
        }
      }
    }

    // ---- stage next tile into the other buffer (disjoint LDS; no barrier) ----
    if (tile + gridDim.x < ntiles) stage(tile + gridDim.x, buf ^ 1);
  }
}

// ---------- 3) node MLP layer 1: g = silu([h, h_agg] @ Wn1 + bn1), bf16-packed ----------
__global__ __launch_bounds__(256) void node_l1_kernel(
    const float* __restrict__ h, const float* __restrict__ h_agg,
    const float* __restrict__ Wn1, const float* __restrict__ bn1,
    unsigned* __restrict__ g, int N)
{
  __shared__ unsigned Wl[256 * HP];           // 64 KB
  int t = threadIdx.x;
  const float2* W2 = (const float2*)Wn1;
  for (int i = t; i < 256 * HP; i += 256) { float2 w = W2[i]; Wl[i] = pack2(w.x, w.y); }
  __syncthreads();

  int wid = blockIdx.x * 4 + (t >> 6);
  int nw  = gridDim.x * 4;
  int jp  = t & 63;
  for (int n = wid; n < N; n += nw) {
    float a0 = bn1[2*jp], a1 = bn1[2*jp + 1];
    const float4* hn = (const float4*)(h + (size_t)n * HH);
    const float4* gn = (const float4*)(h_agg + (size_t)n * HH);
    #pragma unroll 4
    for (int k4 = 0; k4 < 32; ++k4) {
      float4 hv = hn[k4];
      float xs[4] = {hv.x, hv.y, hv.z, hv.w};
      #pragma unroll
      for (int u = 0; u < 4; ++u) {
        unsigned w = Wl[(4*k4 + u) * HP + jp];
        a0 += xs[u] * blo(w); a1 += xs[u] * bhi(w);
      }
    }
    #pragma unroll 4
    for (int k4 = 0; k4 < 32; ++k4) {
      float4 hv = gn[k4];
      float xs[4] = {hv.x, hv.y, hv.z, hv.w};
      #pragma unroll
      for (int u = 0; u < 4; ++u) {
        unsigned w = Wl[(128 + 4*k4 + u) * HP + jp];
        a0 += xs[u] * blo(w); a1 += xs[u] * bhi(w);
      }
    }
    g[(size_t)n * HP + jp] = pack2(silu_f(a0), silu_f(a1));
  }
}

// ---------- 4) node MLP layer 2: h_out = h + g @ Wn2 + bn2 ----------
__global__ __launch_bounds__(256) void node_l2_kernel(
    const unsigned* __restrict__ g, const float* __restrict__ h,
    const float* __restrict__ Wn2, const float* __restrict__ bn2,
    float* __restrict__ hout, int N)
{
  __shared__ unsigned Wl[128 * HP];           // 32 KB
  int t = threadIdx.x;
  const float2* W2 = (const float2*)Wn2;
  for (int i = t; i < 128 * HP; i += 256) { float2 w = W2[i]; Wl[i] = pack2(w.x, w.y); }
  __syncthreads();

  int wid = blockIdx.x * 4 + (t >> 6);
  int nw  = gridDim.x * 4;
  int jp  = t & 63;
  for (int n = wid; n < N; n += nw) {
    float a0 = bn2[2*jp], a1 = bn2[2*jp + 1];
    const uint2* gn = (const uint2*)(g + (size_t)n * HP);
    #pragma unroll 4
    for (int k2 = 0; k2 < 32; ++k2) {
      uint2 gp = gn[k2];                      // 4 bf16 inputs
      float x0 = blo(gp.x), x1 = bhi(gp.x), x2 = blo(gp.y), x3 = bhi(gp.y);
      unsigned w0 = Wl[(4*k2    ) * HP + jp];
      unsigned w1 = Wl[(4*k2 + 1) * HP + jp];
      unsigned w2 = Wl[(4*k2 + 2) * HP + jp];
      unsigned w3 = Wl[(4*k2 + 3) * HP + jp];
      a0 += x0*blo(w0) + x1*blo(w1) + x2*blo(w2) + x3*blo(w3);
      a1 += x0*bhi(w0) + x1*bhi(w1) + x2*bhi(w2) + x3*bhi(w3);
    }
    float2 hv = ((const float2*)h)[(size_t)n * HP + jp];
    ((float2*)hout)[(size_t)n * HP + jp] = make_float2(hv.x + a0, hv.y + a1);
  }
}

// ---------- 5) coords_out = coords + x_agg ----------
__global__ void coords_out_kernel(const float* __restrict__ coords,
                                  const float* __restrict__ x_agg,
                                  float* __restrict__ out, int n3)
{
  int i = blockIdx.x * blockDim.x + threadIdx.x;
  if (i < n3) out[i] = coords[i] + x_agg[i];
}

extern "C" void kernel_launch(void* const* d_in, const int* in_sizes, int n_in,
                              void* d_out, int out_size, void* d_ws, size_t ws_size,
                              hipStream_t stream)
{
  const float* h      = (const float*)d_in[0];
  const float* coords = (const float*)d_in[1];
  const float* afeat  = (const float*)d_in[2];
  const int*   src    = (const int*)d_in[3];
  const int*   dst    = (const int*)d_in[4];
  const float* We1 = (const float*)d_in[5];
  const float* be1 = (const float*)d_in[6];
  const float* We2 = (const float*)d_in[7];
  const float* be2 = (const float*)d_in[8];
  const float* Wa  = (const float*)d_in[9];
  const float* ba  = (const float*)d_in[10];
  const float* Wn1 = (const float*)d_in[11];
  const float* bn1 = (const float*)d_in[12];
  const float* Wn2 = (const float*)d_in[13];
  const float* bn2 = (const float*)d_in[14];
  const float* Wc1 = (const float*)d_in[15];
  const float* bc1 = (const float*)d_in[16];
  const float* Wc2 = (const float*)d_in[17];
  const float* bc2 = (const float*)d_in[18];
  const float* Wc3 = (const float*)d_in[19];

  const int E = in_sizes[3];
  const int N = in_sizes[0] / HH;

  unsigned* A1 = (unsigned*)d_ws;
  unsigned* B1 = A1 + (size_t)N * HP;
  unsigned* Ac = B1 + (size_t)N * HP;
  unsigned* Bc = Ac + (size_t)N * HP;
  float* h_agg = (float*)(Bc + (size_t)N * HP);
  float* x_agg = h_agg + (size_t)N * HH;
  unsigned* gbuf = A1;                        // reuse after edge kernels finish

  hipMemsetAsync(h_agg, 0, ((size_t)N * HH + (size_t)N * 3) * sizeof(float), stream);

  precompute_kernel<<<512, 256, 0, stream>>>(h, We1, be1, A1, B1, N);
  precompute_kernel<<<512, 256, 0, stream>>>(h, Wc1, bc1, Ac, Bc, N);

  edge_kernel<0><<<1024, 256, 0, stream>>>(A1, B1, We1, We2, be2, Wa, ba,
                                           src, dst, coords, afeat, h_agg, E);
  edge_kernel<1><<<1024, 256, 0, stream>>>(Ac, Bc, Wc1, Wc2, bc2, Wc3, nullptr,
                                           src, dst, coords, afeat, x_agg, E);

  node_l1_kernel<<<512, 256, 0, stream>>>(h, h_agg, Wn1, bn1, gbuf, N);
  node_l2_kernel<<<1024, 256, 0, stream>>>(gbuf, h, Wn2, bn2, (float*)d_out, N);
  coords_out_kernel<<<(N * 3 + 255) / 256, 256, 0, stream>>>(
      coords, x_agg, (float*)d_out + (size_t)N * HH, N * 3);
}